// Round 1
// baseline (12748.473 us; speedup 1.0000x reference)
//
#include <hip/hip_runtime.h>
#include <hip/hip_bf16.h>

#define BB   1024
#define TT   64
#define IND  64
#define HH   512
#define G4   2048   // 4*H
#define NLAYER 8
#define NCLS 128

typedef __bf16 bf16x8 __attribute__((ext_vector_type(8)));
typedef float  f32x4  __attribute__((ext_vector_type(4)));

typedef const __attribute__((address_space(1))) void* as1cvp;
typedef __attribute__((address_space(3))) void* as3vp;

__device__ __forceinline__ void gload16(void* lds, const void* g) {
  __builtin_amdgcn_global_load_lds((as1cvp)g, (as3vp)lds, 16, 0, 0);
}

__device__ __forceinline__ float sigmf(float x) { return 1.f / (1.f + __expf(-x)); }

// ---------------- prep kernels ----------------
__global__ void cvt_kernel(const float* __restrict__ s, __bf16* __restrict__ d, int n) {
  int i = blockIdx.x * 256 + threadIdx.x;
  if (i < n) d[i] = (__bf16)s[i];
}

__global__ void bias_prep(const float* __restrict__ bi0, const float* __restrict__ bh0,
                          const float* __restrict__ bi, const float* __restrict__ bh,
                          float* __restrict__ biasb) {
  int i = blockIdx.x * 256 + threadIdx.x;  // 8*2048
  int l = i >> 11, k = i & 2047;
  float v = (l == 0) ? (bi0[k] + bh0[k]) : (bi[(l - 1) * G4 + k] + bh[(l - 1) * G4 + k]);
  biasb[i] = v;
}

__global__ void xpose(const float* __restrict__ x, __bf16* __restrict__ xin) {
  int i = blockIdx.x * 256 + threadIdx.x;  // B*T*64
  int ii = i & 63;
  int t = (i >> 6) & 63;
  int b = i >> 12;
  xin[((size_t)t * BB + b) * IND + ii] = (__bf16)x[i];
}

__global__ void zero_bf16(__bf16* __restrict__ p, int n) {
  int i = blockIdx.x * 256 + threadIdx.x;
  if (i < n) p[i] = (__bf16)0.f;
}

__global__ void zero_f32(float* __restrict__ p, int n) {
  int i = blockIdx.x * 256 + threadIdx.x;
  if (i < n) p[i] = 0.f;
}

// ---------------- input projection GEMM ----------------
// G[m][n] = sum_k A[m][k]*W[n][k] + bias[n]   (A bf16 [Mtot][K], W bf16 [2048][K])
// grid: (Mtot/128, 16), block 256. Output G bf16.
__global__ __launch_bounds__(256, 2) void proj_kernel(
    const __bf16* __restrict__ A, const __bf16* __restrict__ W,
    const float* __restrict__ bias, __bf16* __restrict__ G, int K) {
  __shared__ __bf16 At[128 * 32];
  __shared__ __bf16 Wt[128 * 32];
  const int tid = threadIdx.x;
  const int m0 = blockIdx.x * 128;
  const int n0 = blockIdx.y * 128;
  const int lane = tid & 63, wv = tid >> 6;
  const int qr = lane >> 4, ml = lane & 15;
  const int wr = (wv >> 1) * 64, wc = (wv & 1) * 64;
  const int sr = tid >> 2, sk = (tid & 3) * 8;

  f32x4 acc[4][4];
  for (int i = 0; i < 4; i++)
    for (int j = 0; j < 4; j++)
      for (int r = 0; r < 4; r++) acc[i][j][r] = 0.f;

  const int nk = K >> 5;
  for (int kt = 0; kt < nk; ++kt) {
    const int k0 = kt << 5;
    gload16(&At[tid * 8],        A + (size_t)(m0 + sr) * K      + k0 + sk);
    gload16(&At[2048 + tid * 8], A + (size_t)(m0 + sr + 64) * K + k0 + sk);
    gload16(&Wt[tid * 8],        W + (size_t)(n0 + sr) * K      + k0 + sk);
    gload16(&Wt[2048 + tid * 8], W + (size_t)(n0 + sr + 64) * K + k0 + sk);
    __syncthreads();
    bf16x8 af[4], bfr[4];
    for (int i = 0; i < 4; i++) af[i]  = *(const bf16x8*)&At[(wr + i * 16 + ml) * 32 + qr * 8];
    for (int j = 0; j < 4; j++) bfr[j] = *(const bf16x8*)&Wt[(wc + j * 16 + ml) * 32 + qr * 8];
    for (int i = 0; i < 4; i++)
      for (int j = 0; j < 4; j++)
        acc[i][j] = __builtin_amdgcn_mfma_f32_16x16x32_bf16(af[i], bfr[j], acc[i][j], 0, 0, 0);
    __syncthreads();
  }
  for (int j = 0; j < 4; j++) {
    const int col = n0 + wc + j * 16 + ml;
    const float bv = bias[col];
    for (int i = 0; i < 4; i++) {
      const int row0 = m0 + wr + i * 16 + qr * 4;
      for (int r = 0; r < 4; r++)
        G[(size_t)(row0 + r) * G4 + col] = (__bf16)(acc[i][j][r] + bv);
    }
  }
}

// ---------------- fused recurrent step ----------------
// Tile: 64 b-rows x 128 cols where cols = 4 gates x 32 j. One WG owns all 4 gates
// for its (b,j) cells -> GEMM + cell update fused. grid (16,16), block 256.
__global__ __launch_bounds__(256, 2) void step_kernel(
    const __bf16* __restrict__ hprev,  // [B][512]
    const __bf16* __restrict__ Whh,    // [2048][512]
    const __bf16* __restrict__ Gt,     // [B][2048] pre-activation (x-part + bias)
    float* __restrict__ c,             // [B][512]
    __bf16* __restrict__ hseq_t) {     // [B][512]
  __shared__ union {
    struct { __bf16 At[64 * 32]; __bf16 Wt[128 * 32]; } s;
    float gsm[64 * 128];
  } u;
  const int tid = threadIdx.x;
  const int b0 = blockIdx.x * 64;
  const int j0 = blockIdx.y * 32;
  const int lane = tid & 63, wv = tid >> 6;
  const int qr = lane >> 4, ml = lane & 15;
  const int wr = (wv >> 1) * 32, wc = (wv & 1) * 64;
  const int sr = tid >> 2, sk = (tid & 3) * 8;
  // tile col c -> weight row n = (c>>5)*512 + j0 + (c&31)
  const int wrow0 = ((sr >> 5) * 512) + j0 + (sr & 31);
  const int wrow1 = (((sr + 64) >> 5) * 512) + j0 + ((sr + 64) & 31);

  f32x4 acc[2][4];
  for (int i = 0; i < 2; i++)
    for (int j = 0; j < 4; j++)
      for (int r = 0; r < 4; r++) acc[i][j][r] = 0.f;

  for (int kt = 0; kt < 16; ++kt) {
    const int k0 = kt * 32;
    gload16(&u.s.At[tid * 8],        hprev + (size_t)(b0 + sr) * HH + k0 + sk);
    gload16(&u.s.Wt[tid * 8],        Whh + (size_t)wrow0 * HH + k0 + sk);
    gload16(&u.s.Wt[2048 + tid * 8], Whh + (size_t)wrow1 * HH + k0 + sk);
    __syncthreads();
    bf16x8 af[2], bfr[4];
    for (int i = 0; i < 2; i++) af[i]  = *(const bf16x8*)&u.s.At[(wr + i * 16 + ml) * 32 + qr * 8];
    for (int j = 0; j < 4; j++) bfr[j] = *(const bf16x8*)&u.s.Wt[(wc + j * 16 + ml) * 32 + qr * 8];
    for (int i = 0; i < 2; i++)
      for (int j = 0; j < 4; j++)
        acc[i][j] = __builtin_amdgcn_mfma_f32_16x16x32_bf16(af[i], bfr[j], acc[i][j], 0, 0, 0);
    __syncthreads();
  }
  // dump R to LDS so each thread can gather its 4 gates
  for (int i = 0; i < 2; i++)
    for (int j = 0; j < 4; j++)
      for (int r = 0; r < 4; r++)
        u.gsm[(wr + i * 16 + qr * 4 + r) * 128 + wc + j * 16 + ml] = acc[i][j][r];
  __syncthreads();

  const int jj = tid & 31;
  const int j = j0 + jj;
  for (int kk = 0; kk < 8; ++kk) {
    const int bl = (tid >> 5) + kk * 8;
    const int b = b0 + bl;
    const __bf16* grow = Gt + (size_t)b * G4;
    const float gi = (float)grow[j]          + u.gsm[bl * 128 + jj];
    const float gf = (float)grow[512 + j]    + u.gsm[bl * 128 + 32 + jj];
    const float gg = (float)grow[1024 + j]   + u.gsm[bl * 128 + 64 + jj];
    const float go = (float)grow[1536 + j]   + u.gsm[bl * 128 + 96 + jj];
    const float iv = sigmf(gi), fv = sigmf(gf), gv = tanhf(gg), ov = sigmf(go);
    const size_t ci = (size_t)b * HH + j;
    const float cv = fv * c[ci] + iv * gv;
    c[ci] = cv;
    hseq_t[ci] = (__bf16)(ov * tanhf(cv));
  }
}

// ---------------- FC (bf16 MFMA, K-split) ----------------
// out[b][cc] = sum_{t,j} hseq[t][b][j]*fcw[cc][t*512+j]; grid (16 b-tiles, 16 k-chunks)
__global__ __launch_bounds__(256, 2) void fc_kernel(
    const __bf16* __restrict__ hseq, const __bf16* __restrict__ fcw,
    float* __restrict__ partial) {
  __shared__ __bf16 At[64 * 32];
  __shared__ __bf16 Wt[128 * 32];
  const int tid = threadIdx.x;
  const int b0 = blockIdx.x * 64;
  const int kbase = blockIdx.y * 2048;
  const int lane = tid & 63, wv = tid >> 6;
  const int qr = lane >> 4, ml = lane & 15;
  const int wr = (wv >> 1) * 32, wc = (wv & 1) * 64;
  const int sr = tid >> 2, sk = (tid & 3) * 8;

  f32x4 acc[2][4];
  for (int i = 0; i < 2; i++)
    for (int j = 0; j < 4; j++)
      for (int r = 0; r < 4; r++) acc[i][j][r] = 0.f;

  for (int kt = 0; kt < 64; ++kt) {
    const int k = kbase + kt * 32;
    const int t = k >> 9;
    const int jb = k & 511;
    gload16(&At[tid * 8],        hseq + ((size_t)t * BB + b0 + sr) * HH + jb + sk);
    gload16(&Wt[tid * 8],        fcw + (size_t)sr * (TT * HH) + k + sk);
    gload16(&Wt[2048 + tid * 8], fcw + (size_t)(sr + 64) * (TT * HH) + k + sk);
    __syncthreads();
    bf16x8 af[2], bfr[4];
    for (int i = 0; i < 2; i++) af[i]  = *(const bf16x8*)&At[(wr + i * 16 + ml) * 32 + qr * 8];
    for (int j = 0; j < 4; j++) bfr[j] = *(const bf16x8*)&Wt[(wc + j * 16 + ml) * 32 + qr * 8];
    for (int i = 0; i < 2; i++)
      for (int j = 0; j < 4; j++)
        acc[i][j] = __builtin_amdgcn_mfma_f32_16x16x32_bf16(af[i], bfr[j], acc[i][j], 0, 0, 0);
    __syncthreads();
  }
  for (int i = 0; i < 2; i++)
    for (int j = 0; j < 4; j++)
      for (int r = 0; r < 4; r++)
        partial[((size_t)blockIdx.y * BB + b0 + wr + i * 16 + qr * 4 + r) * NCLS + wc + j * 16 + ml] =
            acc[i][j][r];
}

__global__ void fc_reduce(const float* __restrict__ partial, const float* __restrict__ fcb,
                          float* __restrict__ out) {
  int i = blockIdx.x * 256 + threadIdx.x;  // B*128
  float s = fcb[i & 127];
  for (int p = 0; p < 16; p++) s += partial[(size_t)p * (BB * NCLS) + i];
  out[i] = s;
}

// ---------------- host ----------------
extern "C" void kernel_launch(void* const* d_in, const int* in_sizes, int n_in,
                              void* d_out, int out_size, void* d_ws, size_t ws_size,
                              hipStream_t stream) {
  const float* x    = (const float*)d_in[0];
  const float* wih0 = (const float*)d_in[1];
  const float* whh0 = (const float*)d_in[2];
  const float* bih0 = (const float*)d_in[3];
  const float* bhh0 = (const float*)d_in[4];
  const float* wih  = (const float*)d_in[5];
  const float* whh  = (const float*)d_in[6];
  const float* bih  = (const float*)d_in[7];
  const float* bhh  = (const float*)d_in[8];
  const float* fcw  = (const float*)d_in[9];
  const float* fcb  = (const float*)d_in[10];
  float* out = (float*)d_out;

  size_t off = 0;
  char* base = (char*)d_ws;
  auto carve = [&](size_t bytes) -> char* {
    char* p = base + off;
    off += (bytes + 255) & ~(size_t)255;
    return p;
  };
  __bf16* xin   = (__bf16*)carve((size_t)TT * BB * IND * 2);
  __bf16* wih0b = (__bf16*)carve((size_t)G4 * IND * 2);
  __bf16* whhb  = (__bf16*)carve((size_t)NLAYER * G4 * HH * 2);
  __bf16* wihb  = (__bf16*)carve((size_t)(NLAYER - 1) * G4 * HH * 2);
  __bf16* fcwb  = (__bf16*)carve((size_t)NCLS * TT * HH * 2);
  float*  biasb = (float*)carve((size_t)NLAYER * G4 * 4);
  __bf16* hseqA = (__bf16*)carve((size_t)TT * BB * HH * 2);
  __bf16* hseqB = (__bf16*)carve((size_t)TT * BB * HH * 2);
  __bf16* hzero = (__bf16*)carve((size_t)BB * HH * 2);
  float*  cbuf  = (float*)carve((size_t)BB * HH * 4);
  float*  part  = (float*)carve((size_t)16 * BB * NCLS * 4);
  int chunk = 16;
  while (chunk > 1 && off + (size_t)chunk * BB * G4 * 2 + 256 > ws_size) chunk >>= 1;
  __bf16* Gbuf = (__bf16*)carve((size_t)chunk * BB * G4 * 2);

  // prep: weight/bias conversion, x transpose, h0 zero
  cvt_kernel<<<(G4 * IND + 255) / 256, 256, 0, stream>>>(wih0, wih0b, G4 * IND);
  cvt_kernel<<<(G4 * HH + 255) / 256, 256, 0, stream>>>(whh0, whhb, G4 * HH);
  cvt_kernel<<<(7 * G4 * HH + 255) / 256, 256, 0, stream>>>(whh, whhb + (size_t)G4 * HH, 7 * G4 * HH);
  cvt_kernel<<<(7 * G4 * HH + 255) / 256, 256, 0, stream>>>(wih, wihb, 7 * G4 * HH);
  cvt_kernel<<<(NCLS * TT * HH + 255) / 256, 256, 0, stream>>>(fcw, fcwb, NCLS * TT * HH);
  bias_prep<<<(NLAYER * G4 + 255) / 256, 256, 0, stream>>>(bih0, bhh0, bih, bhh, biasb);
  xpose<<<(TT * BB * IND) / 256, 256, 0, stream>>>(x, xin);
  zero_bf16<<<(BB * HH) / 256, 256, 0, stream>>>(hzero, BB * HH);

  for (int l = 0; l < NLAYER; ++l) {
    zero_f32<<<(BB * HH) / 256, 256, 0, stream>>>(cbuf, BB * HH);
    const __bf16* Ain = (l == 0) ? xin : ((l & 1) ? hseqA : hseqB);
    __bf16* Hout = (l & 1) ? hseqB : hseqA;
    const int K = (l == 0) ? IND : HH;
    const __bf16* Wi = (l == 0) ? wih0b : wihb + (size_t)(l - 1) * G4 * HH;
    const __bf16* Wh = whhb + (size_t)l * G4 * HH;
    const float* bl = biasb + l * G4;
    for (int tc = 0; tc < TT / chunk; ++tc) {
      proj_kernel<<<dim3(chunk * 8, 16), 256, 0, stream>>>(
          Ain + (size_t)tc * chunk * BB * K, Wi, bl, Gbuf, K);
      for (int ts = 0; ts < chunk; ++ts) {
        const int t = tc * chunk + ts;
        const __bf16* hp = (t == 0) ? hzero : Hout + (size_t)(t - 1) * BB * HH;
        step_kernel<<<dim3(16, 16), 256, 0, stream>>>(
            hp, Wh, Gbuf + (size_t)ts * BB * G4, cbuf, Hout + (size_t)t * BB * HH);
      }
    }
  }
  const __bf16* hfinal = ((NLAYER - 1) & 1) ? hseqB : hseqA;  // layer 7 -> hseqB
  fc_kernel<<<dim3(16, 16), 256, 0, stream>>>(hfinal, fcwb, part);
  fc_reduce<<<(BB * NCLS) / 256, 256, 0, stream>>>(part, fcb, out);
}